// Round 6
// baseline (175.994 us; speedup 1.0000x reference)
//
#include <hip/hip_runtime.h>
#include <math.h>
#include <stdint.h>

// B=4, H=16, N=4096, D=128 -> 64 independent scan rows of length 4096.
static constexpr int ROWS = 64;
static constexpr int NSEQ = 4096;
static constexpr int DIM  = 128;
static constexpr int SC   = 8;               // scalar sub-chunk length (= 1 wave's 8 t)
static constexpr int SPR  = NSEQ / SC;       // 512 sub-chunks per row
static constexpr int NSC  = ROWS * SPR;      // 32768 sub-chunks
static constexpr int VC   = 64;              // vector chunk length
static constexpr int VPR  = NSEQ / VC;       // 64 chunks per row
static constexpr int NVC  = ROWS * VPR;      // 4096 vector chunks
static constexpr int SPC  = VC / SC;         // sub-chunks per vector chunk = 8

typedef __attribute__((address_space(3))) uint32_t  lds_u32;
typedef const __attribute__((address_space(1))) uint32_t g_u32;

// ---------------------------------------------------------------------------
// k_alpha v4: persistent 8-tile blocks, double-buffered LDS, counted vmcnt.
// Block = 256 thr (4 waves), tile = 32 timesteps (q 16KB + k 16KB staged).
// Per tile: issue next tile's 8 gload_lds/wave -> s_waitcnt vmcnt(8) (counted,
// never 0 mid-loop) -> raw s_barrier -> compute -> s_barrier. All global
// stores deferred to an epilogue so vmcnt tracks ONLY stage loads (T3/T4).
// LDS: linear dest + inverse-swizzled global source + swizzled read (rule 21).
// Compute: 8 lanes per timestep (16 floats each), dot in-lane, 3-shfl combine;
// per-wave 8-timestep sub-chunk stats via 3-level upper butterfly.
// ---------------------------------------------------------------------------
__global__ __launch_bounds__(256) void k_alpha(
    const float* __restrict__ q, const float* __restrict__ k,
    float* __restrict__ alpha, float* __restrict__ cM, float* __restrict__ cD)
{
    __shared__ float lds[2][8192];           // per buf: q [0,4096), k [4096,8192)
    const int tid   = threadIdx.x;
    const int l     = tid & 63;
    const int w     = tid >> 6;              // wave 0..3
    const int c     = l & 7;                 // 64B chunk of the 512B row
    const int t     = w * 8 + (l >> 3);      // timestep within tile (0..31)
    const int sw    = (t & 7) << 4;
    const int first = blockIdx.x * 8;        // first 32-t tile of this block

    // per-lane swizzled global source offsets (float index) for staging
    int psrc[4];
    #pragma unroll
    for (int i = 0; i < 4; ++i) {
        const int p = w * 4096 + i * 1024 + l * 16;          // linear LDS byte
        psrc[i] = (p ^ (((p >> 9) & 7) << 4)) >> 2;          // involution swz
    }

    float aA[8], sM[8], sD[8];               // deferred outputs (full unroll)

    #define STAGE(BUF, TILE)                                                   \
        do {                                                                   \
            const float* qb_ = q + (size_t)(TILE) * 4096;                      \
            const float* kb_ = k + (size_t)(TILE) * 4096;                      \
            _Pragma("unroll")                                                  \
            for (int i = 0; i < 4; ++i)                                        \
                __builtin_amdgcn_global_load_lds((g_u32*)(qb_ + psrc[i]),      \
                    (lds_u32*)&lds[BUF][(w * 4096 + i * 1024) >> 2], 16, 0, 0);\
            _Pragma("unroll")                                                  \
            for (int i = 0; i < 4; ++i)                                        \
                __builtin_amdgcn_global_load_lds((g_u32*)(kb_ + psrc[i]),      \
                    (lds_u32*)&lds[BUF][4096 + ((w * 4096 + i * 1024) >> 2)],  \
                    16, 0, 0);                                                 \
        } while (0)

    STAGE(0, first);

    #pragma unroll
    for (int j = 0; j < 8; ++j) {
        const int buf = j & 1;
        if (j < 7) {
            STAGE(buf ^ 1, first + j + 1);
            asm volatile("s_waitcnt vmcnt(8)" ::: "memory");  // current tile done
        } else {
            asm volatile("s_waitcnt vmcnt(0)" ::: "memory");
        }
        __builtin_amdgcn_s_barrier();            // raw: no compiler vmcnt(0) drain
        __builtin_amdgcn_sched_barrier(0);       // pin ds_reads after the barrier

        float acc = 0.f;
        #pragma unroll
        for (int jj = 0; jj < 4; ++jj) {
            const int off = t * 512 + (((c << 6) | (jj << 4)) ^ sw);
            const float4 qv = *(const float4*)((const char*)&lds[buf][0] + off);
            const float4 kv = *(const float4*)((const char*)&lds[buf][0] + 16384 + off);
            acc += qv.x * kv.x + qv.y * kv.y + qv.z * kv.z + qv.w * kv.w;
        }
        acc += __shfl_xor(acc, 1);
        acc += __shfl_xor(acc, 2);
        acc += __shfl_xor(acc, 4);               // all 8 lanes of t-group hold alpha_t

        float M = acc;
        M = fmaxf(M, __shfl_xor(M, 8));
        M = fmaxf(M, __shfl_xor(M, 16));
        M = fmaxf(M, __shfl_xor(M, 32));         // max over the wave's 8 timesteps
        float e = (c == 0) ? __expf(acc - M) : 0.f;
        e += __shfl_xor(e, 8);
        e += __shfl_xor(e, 16);
        e += __shfl_xor(e, 32);

        aA[j] = acc; sM[j] = M; sD[j] = e;

        __builtin_amdgcn_sched_barrier(0);       // ds_reads stay before this barrier
        __builtin_amdgcn_s_barrier();            // buf free before j+1 overwrites it
    }
    #undef STAGE

    // epilogue: the only global stores in the kernel
    #pragma unroll
    for (int j = 0; j < 8; ++j) {
        const int tile = first + j;
        if (c == 0) alpha[tile * 32 + t] = aA[j];
        if (l == 0) { cM[tile * 4 + w] = sM[j]; cD[tile * 4 + w] = sD[j]; }
    }
}

// ---------------------------------------------------------------------------
// k_scan: per row (64 blocks):
//  1) thread-0 serial exclusive scan over 512 sub-chunks -> pM,pD (+LDS copy)
//  2) 8-lane-group prefix-max scan per sub-chunk -> coefCW[t] = (c_t, w_t)
// ---------------------------------------------------------------------------
__global__ __launch_bounds__(256) void k_scan(
    const float* __restrict__ alpha, const float* __restrict__ cM,
    const float* __restrict__ cD,
    float* __restrict__ pM, float* __restrict__ pD, float2* __restrict__ coefCW)
{
    __shared__ float lM[SPR], lD[SPR], lpM[SPR];
    const int row = blockIdx.x;
    const int tid = threadIdx.x;

    lM[tid]       = cM[row * SPR + tid];
    lM[tid + 256] = cM[row * SPR + tid + 256];
    lD[tid]       = cD[row * SPR + tid];
    lD[tid + 256] = cD[row * SPR + tid + 256];
    __syncthreads();

    if (tid == 0) {
        float m = -INFINITY, d = 0.f;
        for (int sl = 0; sl < SPR; ++sl) {
            lpM[sl] = m;
            pM[row * SPR + sl] = m; pD[row * SPR + sl] = d;
            const float M = lM[sl], D = lD[sl];
            const float mn = fmaxf(m, M);
            d = d * __expf(m - mn) + D * __expf(M - mn);
            m = mn;
        }
    }
    __syncthreads();

    const int li = tid & 7, grp = tid >> 3;           // 32 groups of 8 lanes
    for (int sl = grp; sl < SPR; sl += 32) {
        const int s = row * SPR + sl;
        const float a = alpha[s * SC + li];
        // inclusive prefix max over the 8 lanes
        float m = a;
        #pragma unroll
        for (int d = 1; d < 8; d <<= 1) {
            const float o = __shfl_up(m, d, 8);
            if (li >= d) m = fmaxf(m, o);
        }
        const float carry = lpM[sl];
        const float mf = fmaxf(m, carry);             // running max incl. carry
        float mp = __shfl_up(mf, 1, 8);
        if (li == 0) mp = carry;                      // m_{t-1}
        const float cc = __expf(mp - mf);             // exp(-inf)=0 at very start
        const float wt = __expf(a - mf);
        coefCW[s * SC + li] = make_float2(cc, wt);
    }
}

// ---------------------------------------------------------------------------
// k_agg: per vector chunk (one wave, lane owns 2 dims): n'_C via the global
// coefficient recurrence seeded 0 (result normalized at chunk-end global max).
// ---------------------------------------------------------------------------
__global__ __launch_bounds__(256) void k_agg(
    const float* __restrict__ v, const float2* __restrict__ coefCW,
    float2* __restrict__ aggN)
{
    const int lane  = threadIdx.x & 63;
    const int C     = blockIdx.x * 4 + (threadIdx.x >> 6);
    const int vbase = C * (VC * DIM);
    const int cbase = __builtin_amdgcn_readfirstlane(C * VC);

    float nx = 0.f, ny = 0.f;
    for (int t0 = 0; t0 < VC; t0 += 8) {
        float2 cw[8], vv[8];
        #pragma unroll
        for (int u = 0; u < 8; ++u) cw[u] = coefCW[cbase + t0 + u];
        #pragma unroll
        for (int u = 0; u < 8; ++u)
            vv[u] = *((const float2*)(v + vbase + (t0 + u) * DIM) + lane);
        #pragma unroll
        for (int u = 0; u < 8; ++u) {
            nx = cw[u].x * nx + cw[u].y * vv[u].x;
            ny = cw[u].x * ny + cw[u].y * vv[u].y;
        }
    }
    aggN[C * (DIM / 2) + lane] = make_float2(nx, ny);
}

// ---------------------------------------------------------------------------
// k_pref: per row, exclusive prefix scan of aggN over 64 chunks (in place),
// combine factor f1 = exp(pM[8C] - pM[8C+8]) (sub-chunk stride = 8 now).
// ---------------------------------------------------------------------------
__global__ __launch_bounds__(128) void k_pref(
    float* __restrict__ aggN, const float* __restrict__ pM)
{
    const int row = blockIdx.x;
    const int d   = threadIdx.x;
    float state = 0.f;
    for (int C0 = 0; C0 < VPR; C0 += 8) {
        float nb[8], f1[8];
        #pragma unroll
        for (int u = 0; u < 8; ++u) {
            const int C  = C0 + u;
            const int Cg = row * VPR + C;
            nb[u] = aggN[Cg * DIM + d];
            const bool last = (C == VPR - 1);
            const float mp  = pM[SPC * Cg];
            const float mp2 = last ? 0.f : pM[SPC * Cg + SPC];
            f1[u] = last ? 0.f : __expf(mp - mp2);
        }
        #pragma unroll
        for (int u = 0; u < 8; ++u) {
            const float nc = nb[u];
            aggN[(row * VPR + C0 + u) * DIM + d] = state;
            state = state * f1[u] + nc;
        }
    }
}

// ---------------------------------------------------------------------------
// k_out: per vector chunk (one wave, lane owns 2 dims): replay the global
// recurrence seeded with the exclusive prefixes; y_t = n_t * rcp(d_t).
// ---------------------------------------------------------------------------
__global__ __launch_bounds__(256) void k_out(
    const float* __restrict__ v, const float2* __restrict__ coefCW,
    const float2* __restrict__ preN, const float* __restrict__ pD,
    float* __restrict__ y)
{
    const int lane  = threadIdx.x & 63;
    const int C     = blockIdx.x * 4 + (threadIdx.x >> 6);
    const int vbase = C * (VC * DIM);
    const int cbase = __builtin_amdgcn_readfirstlane(C * VC);

    float2 n  = preN[C * (DIM / 2) + lane];
    float dch = pD[SPC * C];

    for (int t0 = 0; t0 < VC; t0 += 8) {
        float2 cw[8], vv[8];
        #pragma unroll
        for (int u = 0; u < 8; ++u) cw[u] = coefCW[cbase + t0 + u];
        #pragma unroll
        for (int u = 0; u < 8; ++u)
            vv[u] = *((const float2*)(v + vbase + (t0 + u) * DIM) + lane);
        #pragma unroll
        for (int u = 0; u < 8; ++u) {
            n.x = cw[u].x * n.x + cw[u].y * vv[u].x;
            n.y = cw[u].x * n.y + cw[u].y * vv[u].y;
            dch = cw[u].x * dch + cw[u].y;
            const float rd = __builtin_amdgcn_rcpf(dch);
            *((float2*)(y + vbase + (t0 + u) * DIM) + lane) =
                make_float2(n.x * rd, n.y * rd);
        }
    }
}

// ---------------------------------------------------------------------------
extern "C" void kernel_launch(void* const* d_in, const int* in_sizes, int n_in,
                              void* d_out, int out_size, void* d_ws, size_t ws_size,
                              hipStream_t stream) {
    const float* q = (const float*)d_in[0];
    const float* k = (const float*)d_in[1];
    const float* v = (const float*)d_in[2];
    float* y  = (float*)d_out;
    float* ws = (float*)d_ws;

    // ws layout (floats):
    //  coefCW : 524288    (float2[262144], global per-timestep (c,w))
    //  pM,pD  : 32768 each (exclusive scalar prefixes, SC=8 grain)
    //  cM,cD  : 32768 each (sub-chunk local max / denom)
    //  U      : 524288    (alpha uses first 262144; aggN reuses all of it)
    float*  coefCWf = ws;
    float*  pM      = coefCWf + 2 * ROWS * NSEQ;       // +524288
    float*  pD      = pM + NSC;
    float*  cM      = pD + NSC;
    float*  cD      = cM + NSC;
    float*  U       = cD + NSC;
    float*  alphaA  = U;                               // 262144 floats
    float*  aggNf   = U;                               // 524288 floats (after k_scan)
    float2* coefCW  = (float2*)coefCWf;
    float2* aggN2   = (float2*)aggNf;
    // total: 1,179,648 floats = 4.72 MB

    k_alpha<<<(ROWS * NSEQ / 32) / 8, 256, 0, stream>>>(q, k, alphaA, cM, cD);
    k_scan<<<ROWS, 256, 0, stream>>>(alphaA, cM, cD, pM, pD, coefCW);
    k_agg<<<NVC / 4, 256, 0, stream>>>(v, coefCW, aggN2);
    k_pref<<<ROWS, DIM, 0, stream>>>(aggNf, pM);
    k_out<<<NVC / 4, 256, 0, stream>>>(v, coefCW, aggN2, pD, y);
}

// Round 7
// 175.831 us; speedup vs baseline: 1.0009x; 1.0009x over previous
//
#include <hip/hip_runtime.h>
#include <math.h>
#include <stdint.h>

// B=4, H=16, N=4096, D=128 -> 64 independent scan rows of length 4096.
static constexpr int ROWS = 64;
static constexpr int NSEQ = 4096;
static constexpr int DIM  = 128;
static constexpr int SC   = 16;              // scalar sub-chunk length
static constexpr int SPR  = NSEQ / SC;       // 256 sub-chunks per row
static constexpr int NSC  = ROWS * SPR;      // 16384 sub-chunks
static constexpr int VC   = 64;              // vector chunk length
static constexpr int VPR  = NSEQ / VC;       // 64 chunks per row
static constexpr int NVC  = ROWS * VPR;      // 4096 vector chunks
static constexpr int SPC  = VC / SC;         // sub-chunks per vector chunk = 4

// ---------------------------------------------------------------------------
// k_alpha v5: max-occupancy plain-load version. No LDS, no barriers.
// 32-lane group per 16-timestep chunk; 2 lanes per timestep (64 floats each).
// 16384 chunks -> 2048 blocks of 256 thr = 8 blocks/CU = 32 waves/CU.
// Per batch: 8 independent dwordx4 loads issued BEFORE any FMA
// (sched_barrier(0) pins the boundary so the RA can't serialize them);
// next batch's loads may hoist above this batch's FMAs -> deeper MLP.
// ---------------------------------------------------------------------------
__global__ __launch_bounds__(256) void k_alpha(
    const float* __restrict__ q, const float* __restrict__ k,
    float* __restrict__ alpha, float* __restrict__ cM, float* __restrict__ cD)
{
    const int lane = threadIdx.x & 31;                       // 32-lane group
    const int g    = blockIdx.x * 8 + (threadIdx.x >> 5);    // chunk id (16 t)
    const int t    = lane >> 1;                              // timestep 0..15
    const int h    = lane & 1;                               // row half
    const float* qb = q + (size_t)g * (SC * DIM) + t * DIM + h * 64;
    const float* kb = k + (size_t)g * (SC * DIM) + t * DIM + h * 64;

    float acc = 0.f;
    #pragma unroll
    for (int u0 = 0; u0 < 64; u0 += 16) {
        float4 q4[4], k4[4];
        #pragma unroll
        for (int j = 0; j < 4; ++j) q4[j] = *(const float4*)(qb + u0 + j * 4);
        #pragma unroll
        for (int j = 0; j < 4; ++j) k4[j] = *(const float4*)(kb + u0 + j * 4);
        __builtin_amdgcn_sched_barrier(0);   // all 8 loads issued before FMAs
        #pragma unroll
        for (int j = 0; j < 4; ++j)
            acc += q4[j].x * k4[j].x + q4[j].y * k4[j].y
                 + q4[j].z * k4[j].z + q4[j].w * k4[j].w;
    }
    acc += __shfl_xor(acc, 1);               // alpha_t on both lanes of the pair

    float M = acc;                           // max over the chunk's 16 timesteps
    M = fmaxf(M, __shfl_xor(M, 2));
    M = fmaxf(M, __shfl_xor(M, 4));
    M = fmaxf(M, __shfl_xor(M, 8));
    M = fmaxf(M, __shfl_xor(M, 16));
    float e = (h == 0) ? __expf(acc - M) : 0.f;
    e += __shfl_xor(e, 2);
    e += __shfl_xor(e, 4);
    e += __shfl_xor(e, 8);
    e += __shfl_xor(e, 16);

    if (h == 0) alpha[g * SC + t] = acc;
    if (lane == 0) { cM[g] = M; cD[g] = e; }
}

// ---------------------------------------------------------------------------
// k_scan: per row (64 blocks):
//  1) thread-0 serial exclusive scan over 256 sub-chunks -> pM,pD (+LDS copy)
//  2) 16-lane-group prefix-max scan per sub-chunk -> coefCW[t] = (c_t, w_t)
// ---------------------------------------------------------------------------
__global__ __launch_bounds__(256) void k_scan(
    const float* __restrict__ alpha, const float* __restrict__ cM,
    const float* __restrict__ cD,
    float* __restrict__ pM, float* __restrict__ pD, float2* __restrict__ coefCW)
{
    __shared__ float lM[SPR], lD[SPR], lpM[SPR];
    const int row = blockIdx.x;
    const int tid = threadIdx.x;

    lM[tid] = cM[row * SPR + tid];
    lD[tid] = cD[row * SPR + tid];
    __syncthreads();

    if (tid == 0) {
        float m = -INFINITY, d = 0.f;
        for (int sl = 0; sl < SPR; ++sl) {
            lpM[sl] = m;
            pM[row * SPR + sl] = m; pD[row * SPR + sl] = d;
            const float M = lM[sl], D = lD[sl];
            const float mn = fmaxf(m, M);
            d = d * __expf(m - mn) + D * __expf(M - mn);
            m = mn;
        }
    }
    __syncthreads();

    const int li = tid & 15, grp = tid >> 4;          // 16 groups of 16 lanes
    for (int sl = grp; sl < SPR; sl += 16) {
        const int s = row * SPR + sl;
        const float a = alpha[s * SC + li];
        // inclusive prefix max over the 16 lanes
        float m = a;
        #pragma unroll
        for (int d = 1; d < 16; d <<= 1) {
            const float o = __shfl_up(m, d, 16);
            if (li >= d) m = fmaxf(m, o);
        }
        const float carry = lpM[sl];
        const float mf = fmaxf(m, carry);             // running max incl. carry
        float mp = __shfl_up(mf, 1, 16);
        if (li == 0) mp = carry;                      // m_{t-1}
        const float cc = __expf(mp - mf);             // exp(-inf)=0 at very start
        const float wt = __expf(a - mf);
        coefCW[s * SC + li] = make_float2(cc, wt);
    }
}

// ---------------------------------------------------------------------------
// k_agg: per vector chunk (one wave, lane owns 2 dims): n'_C via the global
// coefficient recurrence seeded 0 (result normalized at chunk-end global max).
// ---------------------------------------------------------------------------
__global__ __launch_bounds__(256) void k_agg(
    const float* __restrict__ v, const float2* __restrict__ coefCW,
    float2* __restrict__ aggN)
{
    const int lane  = threadIdx.x & 63;
    const int C     = blockIdx.x * 4 + (threadIdx.x >> 6);
    const int vbase = C * (VC * DIM);
    const int cbase = __builtin_amdgcn_readfirstlane(C * VC);

    float nx = 0.f, ny = 0.f;
    for (int t0 = 0; t0 < VC; t0 += 8) {
        float2 cw[8], vv[8];
        #pragma unroll
        for (int u = 0; u < 8; ++u) cw[u] = coefCW[cbase + t0 + u];
        #pragma unroll
        for (int u = 0; u < 8; ++u)
            vv[u] = *((const float2*)(v + vbase + (t0 + u) * DIM) + lane);
        #pragma unroll
        for (int u = 0; u < 8; ++u) {
            nx = cw[u].x * nx + cw[u].y * vv[u].x;
            ny = cw[u].x * ny + cw[u].y * vv[u].y;
        }
    }
    aggN[C * (DIM / 2) + lane] = make_float2(nx, ny);
}

// ---------------------------------------------------------------------------
// k_pref: per row, exclusive prefix scan of aggN over 64 chunks (in place),
// combine factor f1 = exp(pM[4C] - pM[4C+4]) (sub-chunk stride = 4).
// ---------------------------------------------------------------------------
__global__ __launch_bounds__(128) void k_pref(
    float* __restrict__ aggN, const float* __restrict__ pM)
{
    const int row = blockIdx.x;
    const int d   = threadIdx.x;
    float state = 0.f;
    for (int C0 = 0; C0 < VPR; C0 += 8) {
        float nb[8], f1[8];
        #pragma unroll
        for (int u = 0; u < 8; ++u) {
            const int C  = C0 + u;
            const int Cg = row * VPR + C;
            nb[u] = aggN[Cg * DIM + d];
            const bool last = (C == VPR - 1);
            const float mp  = pM[SPC * Cg];
            const float mp2 = last ? 0.f : pM[SPC * Cg + SPC];
            f1[u] = last ? 0.f : __expf(mp - mp2);
        }
        #pragma unroll
        for (int u = 0; u < 8; ++u) {
            const float nc = nb[u];
            aggN[(row * VPR + C0 + u) * DIM + d] = state;
            state = state * f1[u] + nc;
        }
    }
}

// ---------------------------------------------------------------------------
// k_out: per vector chunk (one wave, lane owns 2 dims): replay the global
// recurrence seeded with the exclusive prefixes; y_t = n_t * rcp(d_t).
// ---------------------------------------------------------------------------
__global__ __launch_bounds__(256) void k_out(
    const float* __restrict__ v, const float2* __restrict__ coefCW,
    const float2* __restrict__ preN, const float* __restrict__ pD,
    float* __restrict__ y)
{
    const int lane  = threadIdx.x & 63;
    const int C     = blockIdx.x * 4 + (threadIdx.x >> 6);
    const int vbase = C * (VC * DIM);
    const int cbase = __builtin_amdgcn_readfirstlane(C * VC);

    float2 n  = preN[C * (DIM / 2) + lane];
    float dch = pD[SPC * C];

    for (int t0 = 0; t0 < VC; t0 += 8) {
        float2 cw[8], vv[8];
        #pragma unroll
        for (int u = 0; u < 8; ++u) cw[u] = coefCW[cbase + t0 + u];
        #pragma unroll
        for (int u = 0; u < 8; ++u)
            vv[u] = *((const float2*)(v + vbase + (t0 + u) * DIM) + lane);
        #pragma unroll
        for (int u = 0; u < 8; ++u) {
            n.x = cw[u].x * n.x + cw[u].y * vv[u].x;
            n.y = cw[u].x * n.y + cw[u].y * vv[u].y;
            dch = cw[u].x * dch + cw[u].y;
            const float rd = __builtin_amdgcn_rcpf(dch);
            *((float2*)(y + vbase + (t0 + u) * DIM) + lane) =
                make_float2(n.x * rd, n.y * rd);
        }
    }
}

// ---------------------------------------------------------------------------
extern "C" void kernel_launch(void* const* d_in, const int* in_sizes, int n_in,
                              void* d_out, int out_size, void* d_ws, size_t ws_size,
                              hipStream_t stream) {
    const float* q = (const float*)d_in[0];
    const float* k = (const float*)d_in[1];
    const float* v = (const float*)d_in[2];
    float* y  = (float*)d_out;
    float* ws = (float*)d_ws;

    // ws layout (floats):
    //  coefCW : 524288    (float2[262144], global per-timestep (c,w))
    //  pM,pD  : 16384 each (exclusive scalar prefixes, SC=16 grain)
    //  cM,cD  : 16384 each (sub-chunk local max / denom)
    //  U      : 524288    (alpha uses first 262144; aggN reuses all of it)
    float*  coefCWf = ws;
    float*  pM      = coefCWf + 2 * ROWS * NSEQ;       // +524288
    float*  pD      = pM + NSC;
    float*  cM      = pD + NSC;
    float*  cD      = cM + NSC;
    float*  U       = cD + NSC;
    float*  alphaA  = U;                               // 262144 floats
    float*  aggNf   = U;                               // 524288 floats (after k_scan)
    float2* coefCW  = (float2*)coefCWf;
    float2* aggN2   = (float2*)aggNf;
    // total: 1,114,112 floats = 4.46 MB

    k_alpha<<<NSC / 8, 256, 0, stream>>>(q, k, alphaA, cM, cD);
    k_scan<<<ROWS, 256, 0, stream>>>(alphaA, cM, cD, pM, pD, coefCW);
    k_agg<<<NVC / 4, 256, 0, stream>>>(v, coefCW, aggN2);
    k_pref<<<ROWS, DIM, 0, stream>>>(aggNf, pM);
    k_out<<<NVC / 4, 256, 0, stream>>>(v, coefCW, aggN2, pD, y);
}

// Round 8
// 162.258 us; speedup vs baseline: 1.0847x; 1.0837x over previous
//
#include <hip/hip_runtime.h>
#include <math.h>
#include <stdint.h>

// B=4, H=16, N=4096, D=128 -> 64 independent scan rows of length 4096.
static constexpr int ROWS = 64;
static constexpr int NSEQ = 4096;
static constexpr int DIM  = 128;
static constexpr int SC   = 16;              // scalar sub-chunk length
static constexpr int SPR  = NSEQ / SC;       // 256 sub-chunks per row
static constexpr int NSC  = ROWS * SPR;      // 16384 sub-chunks
static constexpr int VC   = 64;              // vector chunk length
static constexpr int VPR  = NSEQ / VC;       // 64 chunks per row
static constexpr int NVC  = ROWS * VPR;      // 4096 vector chunks
static constexpr int SPC  = VC / SC;         // sub-chunks per vector chunk = 4

// ---------------------------------------------------------------------------
// k_alpha v6: coalesced + high-occupancy + ILP shfl trees.
// 32-lane group per 16-timestep chunk; lane = dim-quarter (float4 at 4*lane):
// each load instruction is 32 lanes x 16B = 512B contiguous (full coalescing,
// R1's proven layout). 16384 chunks -> 2048 blocks = 8 blocks/CU.
// Per batch of 4 timesteps: 8 loads issued before any FMA (sched_barrier
// boundary), 4 dots, then 4 INDEPENDENT 5-level shfl_xor trees (ILP covers
// cross-lane latency). After the tree every lane holds alpha_t, so the chunk
// max M needs no extra shuffles (in-lane fmax across t) and the denom D is
// one exp + one 5-tree per chunk.
// ---------------------------------------------------------------------------
__global__ __launch_bounds__(256) void k_alpha(
    const float* __restrict__ q, const float* __restrict__ k,
    float* __restrict__ alpha, float* __restrict__ cM, float* __restrict__ cD)
{
    const int lane = threadIdx.x & 31;                       // 32-lane group
    const int g    = blockIdx.x * 8 + (threadIdx.x >> 5);    // chunk id (16 t)
    const float* qb = q + (size_t)g * (SC * DIM) + 4 * lane;
    const float* kb = k + (size_t)g * (SC * DIM) + 4 * lane;

    float aKeep = 0.f;           // lane l (l<16) keeps alpha for t==l
    float M = -INFINITY;         // chunk max (same in all lanes after trees)

    #pragma unroll
    for (int t0 = 0; t0 < SC; t0 += 4) {
        float4 q4[4], k4[4];
        float  p[4];
        #pragma unroll
        for (int j = 0; j < 4; ++j)
            q4[j] = *(const float4*)(qb + (t0 + j) * DIM);
        #pragma unroll
        for (int j = 0; j < 4; ++j)
            k4[j] = *(const float4*)(kb + (t0 + j) * DIM);
        __builtin_amdgcn_sched_barrier(0);   // all 8 loads issued before FMAs
        #pragma unroll
        for (int j = 0; j < 4; ++j)
            p[j] = q4[j].x * k4[j].x + q4[j].y * k4[j].y
                 + q4[j].z * k4[j].z + q4[j].w * k4[j].w;
        // 4 independent butterfly trees (masks <32 stay within the group)
        #pragma unroll
        for (int m = 16; m >= 1; m >>= 1) {
            #pragma unroll
            for (int j = 0; j < 4; ++j) p[j] += __shfl_xor(p[j], m);
        }
        #pragma unroll
        for (int j = 0; j < 4; ++j) {
            aKeep = (t0 + j == lane) ? p[j] : aKeep;
            M = fmaxf(M, p[j]);
        }
    }

    // denom: one exp + one tree per chunk
    float e = (lane < SC) ? __expf(aKeep - M) : 0.f;
    e += __shfl_xor(e, 16);
    e += __shfl_xor(e, 8);
    e += __shfl_xor(e, 4);
    e += __shfl_xor(e, 2);
    e += __shfl_xor(e, 1);

    if (lane < SC) alpha[g * SC + lane] = aKeep;   // coalesced 64B per group
    if (lane == 0) { cM[g] = M; cD[g] = e; }
}

// ---------------------------------------------------------------------------
// k_scan: per row (64 blocks):
//  1) thread-0 serial exclusive scan over 256 sub-chunks -> pM,pD (+LDS copy)
//  2) 16-lane-group prefix-max scan per sub-chunk -> coefCW[t] = (c_t, w_t)
// ---------------------------------------------------------------------------
__global__ __launch_bounds__(256) void k_scan(
    const float* __restrict__ alpha, const float* __restrict__ cM,
    const float* __restrict__ cD,
    float* __restrict__ pM, float* __restrict__ pD, float2* __restrict__ coefCW)
{
    __shared__ float lM[SPR], lD[SPR], lpM[SPR];
    const int row = blockIdx.x;
    const int tid = threadIdx.x;

    lM[tid] = cM[row * SPR + tid];
    lD[tid] = cD[row * SPR + tid];
    __syncthreads();

    if (tid == 0) {
        float m = -INFINITY, d = 0.f;
        for (int sl = 0; sl < SPR; ++sl) {
            lpM[sl] = m;
            pM[row * SPR + sl] = m; pD[row * SPR + sl] = d;
            const float M = lM[sl], D = lD[sl];
            const float mn = fmaxf(m, M);
            d = d * __expf(m - mn) + D * __expf(M - mn);
            m = mn;
        }
    }
    __syncthreads();

    const int li = tid & 15, grp = tid >> 4;          // 16 groups of 16 lanes
    for (int sl = grp; sl < SPR; sl += 16) {
        const int s = row * SPR + sl;
        const float a = alpha[s * SC + li];
        // inclusive prefix max over the 16 lanes
        float m = a;
        #pragma unroll
        for (int d = 1; d < 16; d <<= 1) {
            const float o = __shfl_up(m, d, 16);
            if (li >= d) m = fmaxf(m, o);
        }
        const float carry = lpM[sl];
        const float mf = fmaxf(m, carry);             // running max incl. carry
        float mp = __shfl_up(mf, 1, 16);
        if (li == 0) mp = carry;                      // m_{t-1}
        const float cc = __expf(mp - mf);             // exp(-inf)=0 at very start
        const float wt = __expf(a - mf);
        coefCW[s * SC + li] = make_float2(cc, wt);
    }
}

// ---------------------------------------------------------------------------
// k_agg: per vector chunk (one wave, lane owns 2 dims): n'_C via the global
// coefficient recurrence seeded 0 (result normalized at chunk-end global max).
// ---------------------------------------------------------------------------
__global__ __launch_bounds__(256) void k_agg(
    const float* __restrict__ v, const float2* __restrict__ coefCW,
    float2* __restrict__ aggN)
{
    const int lane  = threadIdx.x & 63;
    const int C     = blockIdx.x * 4 + (threadIdx.x >> 6);
    const int vbase = C * (VC * DIM);
    const int cbase = __builtin_amdgcn_readfirstlane(C * VC);

    float nx = 0.f, ny = 0.f;
    for (int t0 = 0; t0 < VC; t0 += 8) {
        float2 cw[8], vv[8];
        #pragma unroll
        for (int u = 0; u < 8; ++u) cw[u] = coefCW[cbase + t0 + u];
        #pragma unroll
        for (int u = 0; u < 8; ++u)
            vv[u] = *((const float2*)(v + vbase + (t0 + u) * DIM) + lane);
        #pragma unroll
        for (int u = 0; u < 8; ++u) {
            nx = cw[u].x * nx + cw[u].y * vv[u].x;
            ny = cw[u].x * ny + cw[u].y * vv[u].y;
        }
    }
    aggN[C * (DIM / 2) + lane] = make_float2(nx, ny);
}

// ---------------------------------------------------------------------------
// k_pref: per row, exclusive prefix scan of aggN over 64 chunks (in place),
// combine factor f1 = exp(pM[4C] - pM[4C+4]) (sub-chunk stride = 4).
// ---------------------------------------------------------------------------
__global__ __launch_bounds__(128) void k_pref(
    float* __restrict__ aggN, const float* __restrict__ pM)
{
    const int row = blockIdx.x;
    const int d   = threadIdx.x;
    float state = 0.f;
    for (int C0 = 0; C0 < VPR; C0 += 8) {
        float nb[8], f1[8];
        #pragma unroll
        for (int u = 0; u < 8; ++u) {
            const int C  = C0 + u;
            const int Cg = row * VPR + C;
            nb[u] = aggN[Cg * DIM + d];
            const bool last = (C == VPR - 1);
            const float mp  = pM[SPC * Cg];
            const float mp2 = last ? 0.f : pM[SPC * Cg + SPC];
            f1[u] = last ? 0.f : __expf(mp - mp2);
        }
        #pragma unroll
        for (int u = 0; u < 8; ++u) {
            const float nc = nb[u];
            aggN[(row * VPR + C0 + u) * DIM + d] = state;
            state = state * f1[u] + nc;
        }
    }
}

// ---------------------------------------------------------------------------
// k_out: per vector chunk (one wave, lane owns 2 dims): replay the global
// recurrence seeded with the exclusive prefixes; y_t = n_t * rcp(d_t).
// ---------------------------------------------------------------------------
__global__ __launch_bounds__(256) void k_out(
    const float* __restrict__ v, const float2* __restrict__ coefCW,
    const float2* __restrict__ preN, const float* __restrict__ pD,
    float* __restrict__ y)
{
    const int lane  = threadIdx.x & 63;
    const int C     = blockIdx.x * 4 + (threadIdx.x >> 6);
    const int vbase = C * (VC * DIM);
    const int cbase = __builtin_amdgcn_readfirstlane(C * VC);

    float2 n  = preN[C * (DIM / 2) + lane];
    float dch = pD[SPC * C];

    for (int t0 = 0; t0 < VC; t0 += 8) {
        float2 cw[8], vv[8];
        #pragma unroll
        for (int u = 0; u < 8; ++u) cw[u] = coefCW[cbase + t0 + u];
        #pragma unroll
        for (int u = 0; u < 8; ++u)
            vv[u] = *((const float2*)(v + vbase + (t0 + u) * DIM) + lane);
        #pragma unroll
        for (int u = 0; u < 8; ++u) {
            n.x = cw[u].x * n.x + cw[u].y * vv[u].x;
            n.y = cw[u].x * n.y + cw[u].y * vv[u].y;
            dch = cw[u].x * dch + cw[u].y;
            const float rd = __builtin_amdgcn_rcpf(dch);
            *((float2*)(y + vbase + (t0 + u) * DIM) + lane) =
                make_float2(n.x * rd, n.y * rd);
        }
    }
}

// ---------------------------------------------------------------------------
extern "C" void kernel_launch(void* const* d_in, const int* in_sizes, int n_in,
                              void* d_out, int out_size, void* d_ws, size_t ws_size,
                              hipStream_t stream) {
    const float* q = (const float*)d_in[0];
    const float* k = (const float*)d_in[1];
    const float* v = (const float*)d_in[2];
    float* y  = (float*)d_out;
    float* ws = (float*)d_ws;

    // ws layout (floats):
    //  coefCW : 524288    (float2[262144], global per-timestep (c,w))
    //  pM,pD  : 16384 each (exclusive scalar prefixes, SC=16 grain)
    //  cM,cD  : 16384 each (sub-chunk local max / denom)
    //  U      : 524288    (alpha uses first 262144; aggN reuses all of it)
    float*  coefCWf = ws;
    float*  pM      = coefCWf + 2 * ROWS * NSEQ;       // +524288
    float*  pD      = pM + NSC;
    float*  cM      = pD + NSC;
    float*  cD      = cM + NSC;
    float*  U       = cD + NSC;
    float*  alphaA  = U;                               // 262144 floats
    float*  aggNf   = U;                               // 524288 floats (after k_scan)
    float2* coefCW  = (float2*)coefCWf;
    float2* aggN2   = (float2*)aggNf;
    // total: 1,114,112 floats = 4.46 MB

    k_alpha<<<NSC / 8, 256, 0, stream>>>(q, k, alphaA, cM, cD);
    k_scan<<<ROWS, 256, 0, stream>>>(alphaA, cM, cD, pM, pD, coefCW);
    k_agg<<<NVC / 4, 256, 0, stream>>>(v, coefCW, aggN2);
    k_pref<<<ROWS, DIM, 0, stream>>>(aggNf, pM);
    k_out<<<NVC / 4, 256, 0, stream>>>(v, coefCW, aggN2, pD, y);
}

// Round 9
// 159.585 us; speedup vs baseline: 1.1028x; 1.0167x over previous
//
#include <hip/hip_runtime.h>
#include <math.h>
#include <stdint.h>

// B=4, H=16, N=4096, D=128 -> 64 independent scan rows of length 4096.
static constexpr int ROWS = 64;
static constexpr int NSEQ = 4096;
static constexpr int DIM  = 128;
static constexpr int SC   = 16;              // scalar sub-chunk length
static constexpr int SPR  = NSEQ / SC;       // 256 sub-chunks per row
static constexpr int NSC  = ROWS * SPR;      // 16384 sub-chunks
static constexpr int VC   = 64;              // vector chunk length
static constexpr int VPR  = NSEQ / VC;       // 64 chunks per row
static constexpr int NVC  = ROWS * VPR;      // 4096 vector chunks
static constexpr int SPC  = VC / SC;         // sub-chunks per vector chunk = 4

typedef __attribute__((address_space(3))) uint32_t  lds_u32;
typedef const __attribute__((address_space(1))) uint32_t g_u32;

// ---------------------------------------------------------------------------
// k_alpha v7: MAX-OCCUPANCY staged version. One 256-thr block per 16-t
// sub-chunk; LDS 16.25KB -> 8 blocks/CU = 32 waves/CU (100%). The stage ->
// drain -> compute gaps of one block are covered by the 7 other resident
// blocks (cross-block TLP, m114) instead of intra-wave pipelining (which the
// RA defeated in R3/R4/R7/R8 by collapsing load arrays to minimal VGPRs).
// Stage: gload_lds, linear dest + involution-swizzled source (R5/R6-proven).
// Compute: lane (w,l) -> row=l&15, colblk=(l>>4)+4w: 8 floats q + 8 k via
// swizzled ds_read_b128, dot, fold wave via 2 shfl_xor, fold 4 waves via LDS,
// wave 0 does the 16-lane stats butterflies. No serial chains, no big arrays.
// ---------------------------------------------------------------------------
__global__ __launch_bounds__(256) void k_alpha(
    const float* __restrict__ q, const float* __restrict__ k,
    float* __restrict__ alpha, float* __restrict__ cM, float* __restrict__ cD)
{
    __shared__ float qs[2048];               // 8KB = 16 rows x 512B
    __shared__ float ks[2048];
    __shared__ float aw[4][16];              // per-wave row partial sums
    const int tid = threadIdx.x;
    const int l   = tid & 63;
    const int w   = tid >> 6;                // wave 0..3
    const int s   = blockIdx.x;              // sub-chunk id (16 timesteps)
    const size_t base = (size_t)s * (SC * DIM);   // float offset of tile

    // ---- stage q then k: 2 rounds each, 256 thr x 16B = 4KB per round.
    // linear LDS dest (wave-uniform base + lane*16) + pre-swizzled source.
    #pragma unroll
    for (int r = 0; r < 2; ++r) {
        const int p  = r * 4096 + tid * 16;            // linear byte in 8KB
        const int ps = p ^ (((p >> 9) & 7) << 4);      // involution swizzle
        __builtin_amdgcn_global_load_lds((g_u32*)(q + base + (ps >> 2)),
            (lds_u32*)&qs[(r * 4096 + w * 1024) >> 2], 16, 0, 0);
    }
    #pragma unroll
    for (int r = 0; r < 2; ++r) {
        const int p  = r * 4096 + tid * 16;
        const int ps = p ^ (((p >> 9) & 7) << 4);
        __builtin_amdgcn_global_load_lds((g_u32*)(k + base + (ps >> 2)),
            (lds_u32*)&ks[(r * 4096 + w * 1024) >> 2], 16, 0, 0);
    }
    __syncthreads();   // compiler drains vmcnt(0); other blocks cover the gap

    // ---- partial dot: row = l&15 (timestep), colblk = (l>>4)+4w (8 floats)
    const int row = l & 15;
    const int cb  = (l >> 4) + 4 * w;                  // 0..15
    const int swz = (row & 7) << 4;
    float part = 0.f;
    #pragma unroll
    for (int rr = 0; rr < 2; ++rr) {
        const int off = row * 512 + ((cb * 32 + rr * 16) ^ swz);
        const float4 qv = *(const float4*)((const char*)qs + off);
        const float4 kv = *(const float4*)((const char*)ks + off);
        part += qv.x * kv.x + qv.y * kv.y + qv.z * kv.z + qv.w * kv.w;
    }
    // fold the wave's 4 col-blocks of this row (lanes l, l^16, l^32, l^48)
    part += __shfl_xor(part, 16);
    part += __shfl_xor(part, 32);
    if (l < 16) aw[w][row] = part;
    __syncthreads();

    // ---- wave 0, lanes 0..15: alpha + sub-chunk stats
    if (tid < 16) {
        const float a = aw[0][tid] + aw[1][tid] + aw[2][tid] + aw[3][tid];
        float M = a;                                   // 16-lane butterflies
        M = fmaxf(M, __shfl_xor(M, 1));
        M = fmaxf(M, __shfl_xor(M, 2));
        M = fmaxf(M, __shfl_xor(M, 4));
        M = fmaxf(M, __shfl_xor(M, 8));
        float e = __expf(a - M);
        e += __shfl_xor(e, 1);
        e += __shfl_xor(e, 2);
        e += __shfl_xor(e, 4);
        e += __shfl_xor(e, 8);
        alpha[s * SC + tid] = a;                       // coalesced 64B
        if (tid == 0) { cM[s] = M; cD[s] = e; }
    }
}

// ---------------------------------------------------------------------------
// k_scan: per row (64 blocks):
//  1) thread-0 serial exclusive scan over 256 sub-chunks -> pM,pD (+LDS copy)
//  2) 16-lane-group prefix-max scan per sub-chunk -> coefCW[t] = (c_t, w_t)
// ---------------------------------------------------------------------------
__global__ __launch_bounds__(256) void k_scan(
    const float* __restrict__ alpha, const float* __restrict__ cM,
    const float* __restrict__ cD,
    float* __restrict__ pM, float* __restrict__ pD, float2* __restrict__ coefCW)
{
    __shared__ float lM[SPR], lD[SPR], lpM[SPR];
    const int row = blockIdx.x;
    const int tid = threadIdx.x;

    lM[tid] = cM[row * SPR + tid];
    lD[tid] = cD[row * SPR + tid];
    __syncthreads();

    if (tid == 0) {
        float m = -INFINITY, d = 0.f;
        for (int sl = 0; sl < SPR; ++sl) {
            lpM[sl] = m;
            pM[row * SPR + sl] = m; pD[row * SPR + sl] = d;
            const float M = lM[sl], D = lD[sl];
            const float mn = fmaxf(m, M);
            d = d * __expf(m - mn) + D * __expf(M - mn);
            m = mn;
        }
    }
    __syncthreads();

    const int li = tid & 15, grp = tid >> 4;          // 16 groups of 16 lanes
    for (int sl = grp; sl < SPR; sl += 16) {
        const int s = row * SPR + sl;
        const float a = alpha[s * SC + li];
        // inclusive prefix max over the 16 lanes
        float m = a;
        #pragma unroll
        for (int d = 1; d < 16; d <<= 1) {
            const float o = __shfl_up(m, d, 16);
            if (li >= d) m = fmaxf(m, o);
        }
        const float carry = lpM[sl];
        const float mf = fmaxf(m, carry);             // running max incl. carry
        float mp = __shfl_up(mf, 1, 16);
        if (li == 0) mp = carry;                      // m_{t-1}
        const float cc = __expf(mp - mf);             // exp(-inf)=0 at very start
        const float wt = __expf(a - mf);
        coefCW[s * SC + li] = make_float2(cc, wt);
    }
}

// ---------------------------------------------------------------------------
// k_agg: per vector chunk (one wave, lane owns 2 dims): n'_C via the global
// coefficient recurrence seeded 0 (result normalized at chunk-end global max).
// ---------------------------------------------------------------------------
__global__ __launch_bounds__(256) void k_agg(
    const float* __restrict__ v, const float2* __restrict__ coefCW,
    float2* __restrict__ aggN)
{
    const int lane  = threadIdx.x & 63;
    const int C     = blockIdx.x * 4 + (threadIdx.x >> 6);
    const int vbase = C * (VC * DIM);
    const int cbase = __builtin_amdgcn_readfirstlane(C * VC);

    float nx = 0.f, ny = 0.f;
    for (int t0 = 0; t0 < VC; t0 += 8) {
        float2 cw[8], vv[8];
        #pragma unroll
        for (int u = 0; u < 8; ++u) cw[u] = coefCW[cbase + t0 + u];
        #pragma unroll
        for (int u = 0; u < 8; ++u)
            vv[u] = *((const float2*)(v + vbase + (t0 + u) * DIM) + lane);
        #pragma unroll
        for (int u = 0; u < 8; ++u) {
            nx = cw[u].x * nx + cw[u].y * vv[u].x;
            ny = cw[u].x * ny + cw[u].y * vv[u].y;
        }
    }
    aggN[C * (DIM / 2) + lane] = make_float2(nx, ny);
}

// ---------------------------------------------------------------------------
// k_pref: per row, exclusive prefix scan of aggN over 64 chunks (in place),
// combine factor f1 = exp(pM[4C] - pM[4C+4]) (sub-chunk stride = 4).
// ---------------------------------------------------------------------------
__global__ __launch_bounds__(128) void k_pref(
    float* __restrict__ aggN, const float* __restrict__ pM)
{
    const int row = blockIdx.x;
    const int d   = threadIdx.x;
    float state = 0.f;
    for (int C0 = 0; C0 < VPR; C0 += 8) {
        float nb[8], f1[8];
        #pragma unroll
        for (int u = 0; u < 8; ++u) {
            const int C  = C0 + u;
            const int Cg = row * VPR + C;
            nb[u] = aggN[Cg * DIM + d];
            const bool last = (C == VPR - 1);
            const float mp  = pM[SPC * Cg];
            const float mp2 = last ? 0.f : pM[SPC * Cg + SPC];
            f1[u] = last ? 0.f : __expf(mp - mp2);
        }
        #pragma unroll
        for (int u = 0; u < 8; ++u) {
            const float nc = nb[u];
            aggN[(row * VPR + C0 + u) * DIM + d] = state;
            state = state * f1[u] + nc;
        }
    }
}

// ---------------------------------------------------------------------------
// k_out: per vector chunk (one wave, lane owns 2 dims): replay the global
// recurrence seeded with the exclusive prefixes; y_t = n_t * rcp(d_t).
// ---------------------------------------------------------------------------
__global__ __launch_bounds__(256) void k_out(
    const float* __restrict__ v, const float2* __restrict__ coefCW,
    const float2* __restrict__ preN, const float* __restrict__ pD,
    float* __restrict__ y)
{
    const int lane  = threadIdx.x & 63;
    const int C     = blockIdx.x * 4 + (threadIdx.x >> 6);
    const int vbase = C * (VC * DIM);
    const int cbase = __builtin_amdgcn_readfirstlane(C * VC);

    float2 n  = preN[C * (DIM / 2) + lane];
    float dch = pD[SPC * C];

    for (int t0 = 0; t0 < VC; t0 += 8) {
        float2 cw[8], vv[8];
        #pragma unroll
        for (int u = 0; u < 8; ++u) cw[u] = coefCW[cbase + t0 + u];
        #pragma unroll
        for (int u = 0; u < 8; ++u)
            vv[u] = *((const float2*)(v + vbase + (t0 + u) * DIM) + lane);
        #pragma unroll
        for (int u = 0; u < 8; ++u) {
            n.x = cw[u].x * n.x + cw[u].y * vv[u].x;
            n.y = cw[u].x * n.y + cw[u].y * vv[u].y;
            dch = cw[u].x * dch + cw[u].y;
            const float rd = __builtin_amdgcn_rcpf(dch);
            *((float2*)(y + vbase + (t0 + u) * DIM) + lane) =
                make_float2(n.x * rd, n.y * rd);
        }
    }
}

// ---------------------------------------------------------------------------
extern "C" void kernel_launch(void* const* d_in, const int* in_sizes, int n_in,
                              void* d_out, int out_size, void* d_ws, size_t ws_size,
                              hipStream_t stream) {
    const float* q = (const float*)d_in[0];
    const float* k = (const float*)d_in[1];
    const float* v = (const float*)d_in[2];
    float* y  = (float*)d_out;
    float* ws = (float*)d_ws;

    // ws layout (floats):
    //  coefCW : 524288    (float2[262144], global per-timestep (c,w))
    //  pM,pD  : 16384 each (exclusive scalar prefixes, SC=16 grain)
    //  cM,cD  : 16384 each (sub-chunk local max / denom)
    //  U      : 524288    (alpha uses first 262144; aggN reuses all of it)
    float*  coefCWf = ws;
    float*  pM      = coefCWf + 2 * ROWS * NSEQ;       // +524288
    float*  pD      = pM + NSC;
    float*  cM      = pD + NSC;
    float*  cD      = cM + NSC;
    float*  U       = cD + NSC;
    float*  alphaA  = U;                               // 262144 floats
    float*  aggNf   = U;                               // 524288 floats (after k_scan)
    float2* coefCW  = (float2*)coefCWf;
    float2* aggN2   = (float2*)aggNf;
    // total: 1,114,112 floats = 4.46 MB

    k_alpha<<<NSC, 256, 0, stream>>>(q, k, alphaA, cM, cD);
    k_scan<<<ROWS, 256, 0, stream>>>(alphaA, cM, cD, pM, pD, coefCW);
    k_agg<<<NVC / 4, 256, 0, stream>>>(v, coefCW, aggN2);
    k_pref<<<ROWS, DIM, 0, stream>>>(aggNf, pM);
    k_out<<<NVC / 4, 256, 0, stream>>>(v, coefCW, aggN2, pD, y);
}

// Round 10
// 158.220 us; speedup vs baseline: 1.1123x; 1.0086x over previous
//
#include <hip/hip_runtime.h>
#include <math.h>
#include <stdint.h>

// B=4, H=16, N=4096, D=128 -> 64 independent scan rows of length 4096.
static constexpr int ROWS = 64;
static constexpr int NSEQ = 4096;
static constexpr int DIM  = 128;
static constexpr int SC   = 16;              // scalar sub-chunk length
static constexpr int SPR  = NSEQ / SC;       // 256 sub-chunks per row
static constexpr int NSC  = ROWS * SPR;      // 16384 sub-chunks
static constexpr int VC   = 64;              // vector chunk length
static constexpr int VPR  = NSEQ / VC;       // 64 chunks per row
static constexpr int NVC  = ROWS * VPR;      // 4096 vector chunks
static constexpr int SPC  = VC / SC;         // sub-chunks per vector chunk = 4

typedef __attribute__((address_space(3))) uint32_t  lds_u32;
typedef const __attribute__((address_space(1))) uint32_t g_u32;

// ---------------------------------------------------------------------------
// k_alpha v8: v7 + PHASE-SPLIT q/k staging (DRAM bank-thrash fix).
// q and k sit exactly 2^26 B apart -> q[x],k[x] share channel+bank, different
// row. All previous variants kept both streams in flight lockstep -> every
// bank alternated rows -> ~2x DRAM efficiency loss (2.7 TB/s wall, occupancy-
// insensitive: R3/R5/R6/R7/R8/R9 evidence). Fix: stage the q-tile, DRAIN
// (vmcnt(0) via __syncthreads), then stage the k-tile. Within a block the two
// streams never coexist; across blocks tiles differ (8KB granularity) so low
// address bits decorrelate. 8 blocks/CU cover the added per-block latency.
// ---------------------------------------------------------------------------
__global__ __launch_bounds__(256) void k_alpha(
    const float* __restrict__ q, const float* __restrict__ k,
    float* __restrict__ alpha, float* __restrict__ cM, float* __restrict__ cD)
{
    __shared__ float qs[2048];               // 8KB = 16 rows x 512B
    __shared__ float ks[2048];
    __shared__ float aw[4][16];              // per-wave row partial sums
    const int tid = threadIdx.x;
    const int l   = tid & 63;
    const int w   = tid >> 6;                // wave 0..3
    const int s   = blockIdx.x;              // sub-chunk id (16 timesteps)
    const size_t base = (size_t)s * (SC * DIM);   // float offset of tile

    // ---- phase A: stage q ONLY (single stream), then drain.
    #pragma unroll
    for (int r = 0; r < 2; ++r) {
        const int p  = r * 4096 + tid * 16;            // linear byte in 8KB
        const int ps = p ^ (((p >> 9) & 7) << 4);      // involution swizzle
        __builtin_amdgcn_global_load_lds((g_u32*)(q + base + (ps >> 2)),
            (lds_u32*)&qs[(r * 4096 + w * 1024) >> 2], 16, 0, 0);
    }
    __syncthreads();   // compiler emits s_waitcnt vmcnt(0) before s_barrier

    // ---- phase B: stage k ONLY, then drain.
    #pragma unroll
    for (int r = 0; r < 2; ++r) {
        const int p  = r * 4096 + tid * 16;
        const int ps = p ^ (((p >> 9) & 7) << 4);
        __builtin_amdgcn_global_load_lds((g_u32*)(k + base + (ps >> 2)),
            (lds_u32*)&ks[(r * 4096 + w * 1024) >> 2], 16, 0, 0);
    }
    __syncthreads();

    // ---- partial dot: row = l&15 (timestep), colblk = (l>>4)+4w (8 floats)
    const int row = l & 15;
    const int cb  = (l >> 4) + 4 * w;                  // 0..15
    const int swz = (row & 7) << 4;
    float part = 0.f;
    #pragma unroll
    for (int rr = 0; rr < 2; ++rr) {
        const int off = row * 512 + ((cb * 32 + rr * 16) ^ swz);
        const float4 qv = *(const float4*)((const char*)qs + off);
        const float4 kv = *(const float4*)((const char*)ks + off);
        part += qv.x * kv.x + qv.y * kv.y + qv.z * kv.z + qv.w * kv.w;
    }
    // fold the wave's 4 col-blocks of this row (lanes l, l^16, l^32, l^48)
    part += __shfl_xor(part, 16);
    part += __shfl_xor(part, 32);
    if (l < 16) aw[w][row] = part;
    __syncthreads();

    // ---- wave 0, lanes 0..15: alpha + sub-chunk stats
    if (tid < 16) {
        const float a = aw[0][tid] + aw[1][tid] + aw[2][tid] + aw[3][tid];
        float M = a;                                   // 16-lane butterflies
        M = fmaxf(M, __shfl_xor(M, 1));
        M = fmaxf(M, __shfl_xor(M, 2));
        M = fmaxf(M, __shfl_xor(M, 4));
        M = fmaxf(M, __shfl_xor(M, 8));
        float e = __expf(a - M);
        e += __shfl_xor(e, 1);
        e += __shfl_xor(e, 2);
        e += __shfl_xor(e, 4);
        e += __shfl_xor(e, 8);
        alpha[s * SC + tid] = a;                       // coalesced 64B
        if (tid == 0) { cM[s] = M; cD[s] = e; }
    }
}

// ---------------------------------------------------------------------------
// k_scan: per row (64 blocks):
//  1) thread-0 serial exclusive scan over 256 sub-chunks -> pM,pD (+LDS copy)
//  2) 16-lane-group prefix-max scan per sub-chunk -> coefCW[t] = (c_t, w_t)
// ---------------------------------------------------------------------------
__global__ __launch_bounds__(256) void k_scan(
    const float* __restrict__ alpha, const float* __restrict__ cM,
    const float* __restrict__ cD,
    float* __restrict__ pM, float* __restrict__ pD, float2* __restrict__ coefCW)
{
    __shared__ float lM[SPR], lD[SPR], lpM[SPR];
    const int row = blockIdx.x;
    const int tid = threadIdx.x;

    lM[tid] = cM[row * SPR + tid];
    lD[tid] = cD[row * SPR + tid];
    __syncthreads();

    if (tid == 0) {
        float m = -INFINITY, d = 0.f;
        for (int sl = 0; sl < SPR; ++sl) {
            lpM[sl] = m;
            pM[row * SPR + sl] = m; pD[row * SPR + sl] = d;
            const float M = lM[sl], D = lD[sl];
            const float mn = fmaxf(m, M);
            d = d * __expf(m - mn) + D * __expf(M - mn);
            m = mn;
        }
    }
    __syncthreads();

    const int li = tid & 15, grp = tid >> 4;          // 16 groups of 16 lanes
    for (int sl = grp; sl < SPR; sl += 16) {
        const int s = row * SPR + sl;
        const float a = alpha[s * SC + li];
        // inclusive prefix max over the 16 lanes
        float m = a;
        #pragma unroll
        for (int d = 1; d < 16; d <<= 1) {
            const float o = __shfl_up(m, d, 16);
            if (li >= d) m = fmaxf(m, o);
        }
        const float carry = lpM[sl];
        const float mf = fmaxf(m, carry);             // running max incl. carry
        float mp = __shfl_up(mf, 1, 16);
        if (li == 0) mp = carry;                      // m_{t-1}
        const float cc = __expf(mp - mf);             // exp(-inf)=0 at very start
        const float wt = __expf(a - mf);
        coefCW[s * SC + li] = make_float2(cc, wt);
    }
}

// ---------------------------------------------------------------------------
// k_agg: per vector chunk (one wave, lane owns 2 dims): n'_C via the global
// coefficient recurrence seeded 0 (result normalized at chunk-end global max).
// ---------------------------------------------------------------------------
__global__ __launch_bounds__(256) void k_agg(
    const float* __restrict__ v, const float2* __restrict__ coefCW,
    float2* __restrict__ aggN)
{
    const int lane  = threadIdx.x & 63;
    const int C     = blockIdx.x * 4 + (threadIdx.x >> 6);
    const int vbase = C * (VC * DIM);
    const int cbase = __builtin_amdgcn_readfirstlane(C * VC);

    float nx = 0.f, ny = 0.f;
    for (int t0 = 0; t0 < VC; t0 += 8) {
        float2 cw[8], vv[8];
        #pragma unroll
        for (int u = 0; u < 8; ++u) cw[u] = coefCW[cbase + t0 + u];
        #pragma unroll
        for (int u = 0; u < 8; ++u)
            vv[u] = *((const float2*)(v + vbase + (t0 + u) * DIM) + lane);
        #pragma unroll
        for (int u = 0; u < 8; ++u) {
            nx = cw[u].x * nx + cw[u].y * vv[u].x;
            ny = cw[u].x * ny + cw[u].y * vv[u].y;
        }
    }
    aggN[C * (DIM / 2) + lane] = make_float2(nx, ny);
}

// ---------------------------------------------------------------------------
// k_pref: per row, exclusive prefix scan of aggN over 64 chunks (in place),
// combine factor f1 = exp(pM[4C] - pM[4C+4]) (sub-chunk stride = 4).
// ---------------------------------------------------------------------------
__global__ __launch_bounds__(128) void k_pref(
    float* __restrict__ aggN, const float* __restrict__ pM)
{
    const int row = blockIdx.x;
    const int d   = threadIdx.x;
    float state = 0.f;
    for (int C0 = 0; C0 < VPR; C0 += 8) {
        float nb[8], f1[8];
        #pragma unroll
        for (int u = 0; u < 8; ++u) {
            const int C  = C0 + u;
            const int Cg = row * VPR + C;
            nb[u] = aggN[Cg * DIM + d];
            const bool last = (C == VPR - 1);
            const float mp  = pM[SPC * Cg];
            const float mp2 = last ? 0.f : pM[SPC * Cg + SPC];
            f1[u] = last ? 0.f : __expf(mp - mp2);
        }
        #pragma unroll
        for (int u = 0; u < 8; ++u) {
            const float nc = nb[u];
            aggN[(row * VPR + C0 + u) * DIM + d] = state;
            state = state * f1[u] + nc;
        }
    }
}

// ---------------------------------------------------------------------------
// k_out: per vector chunk (one wave, lane owns 2 dims): replay the global
// recurrence seeded with the exclusive prefixes; y_t = n_t * rcp(d_t).
// ---------------------------------------------------------------------------
__global__ __launch_bounds__(256) void k_out(
    const float* __restrict__ v, const float2* __restrict__ coefCW,
    const float2* __restrict__ preN, const float* __restrict__ pD,
    float* __restrict__ y)
{
    const int lane  = threadIdx.x & 63;
    const int C     = blockIdx.x * 4 + (threadIdx.x >> 6);
    const int vbase = C * (VC * DIM);
    const int cbase = __builtin_amdgcn_readfirstlane(C * VC);

    float2 n  = preN[C * (DIM / 2) + lane];
    float dch = pD[SPC * C];

    for (int t0 = 0; t0 < VC; t0 += 8) {
        float2 cw[8], vv[8];
        #pragma unroll
        for (int u = 0; u < 8; ++u) cw[u] = coefCW[cbase + t0 + u];
        #pragma unroll
        for (int u = 0; u < 8; ++u)
            vv[u] = *((const float2*)(v + vbase + (t0 + u) * DIM) + lane);
        #pragma unroll
        for (int u = 0; u < 8; ++u) {
            n.x = cw[u].x * n.x + cw[u].y * vv[u].x;
            n.y = cw[u].x * n.y + cw[u].y * vv[u].y;
            dch = cw[u].x * dch + cw[u].y;
            const float rd = __builtin_amdgcn_rcpf(dch);
            *((float2*)(y + vbase + (t0 + u) * DIM) + lane) =
                make_float2(n.x * rd, n.y * rd);
        }
    }
}

// ---------------------------------------------------------------------------
extern "C" void kernel_launch(void* const* d_in, const int* in_sizes, int n_in,
                              void* d_out, int out_size, void* d_ws, size_t ws_size,
                              hipStream_t stream) {
    const float* q = (const float*)d_in[0];
    const float* k = (const float*)d_in[1];
    const float* v = (const float*)d_in[2];
    float* y  = (float*)d_out;
    float* ws = (float*)d_ws;

    // ws layout (floats):
    //  coefCW : 524288    (float2[262144], global per-timestep (c,w))
    //  pM,pD  : 16384 each (exclusive scalar prefixes, SC=16 grain)
    //  cM,cD  : 16384 each (sub-chunk local max / denom)
    //  U      : 524288    (alpha uses first 262144; aggN reuses all of it)
    float*  coefCWf = ws;
    float*  pM      = coefCWf + 2 * ROWS * NSEQ;       // +524288
    float*  pD      = pM + NSC;
    float*  cM      = pD + NSC;
    float*  cD      = cM + NSC;
    float*  U       = cD + NSC;
    float*  alphaA  = U;                               // 262144 floats
    float*  aggNf   = U;                               // 524288 floats (after k_scan)
    float2* coefCW  = (float2*)coefCWf;
    float2* aggN2   = (float2*)aggNf;
    // total: 1,114,112 floats = 4.46 MB

    k_alpha<<<NSC, 256, 0, stream>>>(q, k, alphaA, cM, cD);
    k_scan<<<ROWS, 256, 0, stream>>>(alphaA, cM, cD, pM, pD, coefCW);
    k_agg<<<NVC / 4, 256, 0, stream>>>(v, coefCW, aggN2);
    k_pref<<<ROWS, DIM, 0, stream>>>(aggNf, pM);
    k_out<<<NVC / 4, 256, 0, stream>>>(v, coefCW, aggN2, pD, y);
}